// Round 16
// baseline (199.298 us; speedup 1.0000x reference)
//
#include <hip/hip_runtime.h>
#include <hip/hip_bf16.h>

typedef __attribute__((ext_vector_type(4))) int i32x4;
typedef __attribute__((ext_vector_type(16))) int i32x16;

#define M_DIM 8192
#define N_DIM 8192
#define K_DIM 2048
#define WCOUNT (N_DIM * K_DIM)

// Fragment-major layout: frag[t32][kc][l] : byte = t32*65536 + kc*512 + l*16.
// One 32x32x32 MFMA operand fragment = contiguous 1024-B wave access.

// ---------------- kernel 1: per-block partial sums of |w| ----------------
__global__ __launch_bounds__(256) void k_abs_partial(const float* __restrict__ w,
                                                     float* __restrict__ part) {
    int tid = blockIdx.x * 256 + threadIdx.x;
    const float4* w4 = (const float4*)w;
    float s = 0.0f;
    const int total4 = WCOUNT / 4;
    for (int i = tid; i < total4; i += 2048 * 256) {
        float4 v = w4[i];
        s += fabsf(v.x) + fabsf(v.y) + fabsf(v.z) + fabsf(v.w);
    }
    #pragma unroll
    for (int off = 1; off < 64; off <<= 1) s += __shfl_xor(s, off);
    __shared__ float red[4];
    if ((threadIdx.x & 63) == 0) red[threadIdx.x >> 6] = s;
    __syncthreads();
    if (threadIdx.x == 0)
        part[blockIdx.x] = (red[0] + red[1]) + (red[2] + red[3]);
}

// ---------------- kernel 2: deterministic final reduce -> sum|w| ----------------
__global__ __launch_bounds__(256) void k_abs_final(const float* __restrict__ part,
                                                   float* __restrict__ sum) {
    int t = threadIdx.x;
    float s = 0.0f;
    #pragma unroll
    for (int i = 0; i < 8; i++) s += part[t + i * 256];
    #pragma unroll
    for (int off = 1; off < 64; off <<= 1) s += __shfl_xor(s, off);
    __shared__ float red[4];
    if ((t & 63) == 0) red[t >> 6] = s;
    __syncthreads();
    if (t == 0) sum[0] = (red[0] + red[1]) + (red[2] + red[3]);
}

// -------- kernel 3: ternary weight quant -> int8, fragment-major --------
__global__ __launch_bounds__(256) void k_wquant(const float* __restrict__ w,
                                                const float* __restrict__ sum,
                                                signed char* __restrict__ wqf) {
    const float thr = 0.5f * (sum[0] * (1.0f / 16777216.0f));
    const int g = blockIdx.x * 256 + threadIdx.x;
    const int n = g >> 7;
    const int kc = g & 127;
    const float4* wr = (const float4*)(w + (size_t)n * K_DIM + kc * 16);
    union { signed char c[16]; uint4 v; } pk;
    #pragma unroll
    for (int q = 0; q < 4; q++) {
        float4 v = wr[q];
        pk.c[q * 4 + 0] = v.x > thr ? 1 : (v.x < -thr ? -1 : 0);
        pk.c[q * 4 + 1] = v.y > thr ? 1 : (v.y < -thr ? -1 : 0);
        pk.c[q * 4 + 2] = v.z > thr ? 1 : (v.z < -thr ? -1 : 0);
        pk.c[q * 4 + 3] = v.w > thr ? 1 : (v.w < -thr ? -1 : 0);
    }
    *(uint4*)(wqf + (size_t)(n >> 5) * 65536 + kc * 512 + (n & 31) * 16) = pk.v;
}

// -------- kernel 4: activation quant -> int8 fragment-major + coef --------
__global__ __launch_bounds__(256) void k_xquant(const float* __restrict__ x,
                                                const float* __restrict__ sum,
                                                signed char* __restrict__ xqf,
                                                float* __restrict__ coef) {
    const int row = blockIdx.x;
    const int t = threadIdx.x;
    const float4* xr = (const float4*)(x + (size_t)row * K_DIM);
    float4 a = xr[t * 2];
    float4 b = xr[t * 2 + 1];
    float m = fmaxf(fmaxf(fmaxf(fabsf(a.x), fabsf(a.y)), fmaxf(fabsf(a.z), fabsf(a.w))),
                    fmaxf(fmaxf(fabsf(b.x), fabsf(b.y)), fmaxf(fabsf(b.z), fabsf(b.w))));
    #pragma unroll
    for (int off = 1; off < 64; off <<= 1) m = fmaxf(m, __shfl_xor(m, off));
    __shared__ float red[4];
    if ((t & 63) == 0) red[t >> 6] = m;
    __syncthreads();
    m = fmaxf(fmaxf(red[0], red[1]), fmaxf(red[2], red[3]));
    const float sc = fmaxf(m, 1e-5f);
    if (t == 0) coef[row] = (sum[0] * (1.0f / 16777216.0f)) / sc;
    const float r = 127.0f / sc;
    float q[8] = {a.x, a.y, a.z, a.w, b.x, b.y, b.z, b.w};
    union { signed char c[8]; uint2 v; } pk;
    #pragma unroll
    for (int j = 0; j < 8; j++) {
        float v = rintf(q[j] * r);
        v = fminf(fmaxf(v, -127.0f), 127.0f);
        pk.c[j] = (signed char)v;
    }
    *(uint2*)(xqf + (size_t)(row >> 5) * 65536 + (t >> 1) * 512
              + (row & 31) * 16 + (t & 1) * 8) = pk.v;
}

#define GLDS16(g, l)                                                                   \
    __builtin_amdgcn_global_load_lds((const __attribute__((address_space(1))) void*)(g), \
                                     (__attribute__((address_space(3))) void*)(l), 16, 0, 0)
#define BAR __builtin_amdgcn_s_barrier()
#define VMW(n) asm volatile("s_waitcnt vmcnt(" #n ")" ::: "memory")

// ---------------- kernel 5: 128x128 i8 GEMM, stage-early single-barrier ring ----
// Delta vs R12 (the ONE change): step reordered to {STG(kt+2) | MMK(kt) | VMW(4)
// | BAR} — stage issued BEFORE compute (T3 recipe), ONE barrier per K-tile.
//  - WAR: STG targets the buf read at step kt-1; those reads were lgkm-forced
//    before each wave's MFMAs, which precede BAR(kt-1); every wave passes
//    BAR(kt-1) before any wave issues the STG. Safe with a single barrier.
//  - RAW: VMW(4) leaves the just-issued kt+2 outstanding and forces kt+1,
//    which was issued at step kt-1 start -> ~2 full steps (~1600 cy) of flight;
//    DMA lands under MFMA instead of serializing between barriers (R13's
//    ~10.5us/round staging adder = DMA served serially in the old BAR;STG;VMW;BAR
//    sandwich). Collective gate: all waves pass their own VMW+BAR before any
//    wave reads kt+1.
// Ring: 3 bufs x 16 KB (48 KB LDS, 3 blocks/CU at 72+64=136 regs). Epilogue:
// R12 direct nontemporal stores (R14's LDS-transpose regressed).
__global__ __launch_bounds__(256, 3) void k_gemm(const signed char* __restrict__ xqf,
                                                 const signed char* __restrict__ wqf,
                                                 const float* __restrict__ coef,
                                                 float* __restrict__ out) {
    __shared__ signed char lds[49152];

    const int t = threadIdx.x;
    const int lane = t & 63;
    const int wid = t >> 6;
    const int wm = wid >> 1;
    const int wn = wid & 1;
    const int l31 = lane & 31;
    const int kg = lane >> 5;

    // L2 mapping: XCD x owns brows [8x,8x+8); per XCD, groups of 4 bcols sweep.
    const int bid = blockIdx.x;
    const int xcd = bid & 7;
    const int idx = bid >> 3;
    const int grp = idx >> 5;
    const int w_ = idx & 31;
    const int bcol = grp * 4 + (w_ & 3);
    const int brow = xcd * 8 + ((w_ >> 2) & 7);

    const signed char* aSrc0 = xqf + (size_t)(brow * 4 + (t >> 7)) * 65536 + (t & 127) * 16;
    const signed char* aSrc1 = xqf + (size_t)(brow * 4 + 2 + (t >> 7)) * 65536 + (t & 127) * 16;
    const signed char* bSrc0 = wqf + (size_t)(bcol * 4 + (t >> 7)) * 65536 + (t & 127) * 16;
    const signed char* bSrc1 = wqf + (size_t)(bcol * 4 + 2 + (t >> 7)) * 65536 + (t & 127) * 16;
    const int dst0 = wid * 1024;
    const int dst1 = 4096 + wid * 1024;

#define STG(bufc, kt) do {                                                         \
        GLDS16(aSrc0 + (size_t)(kt) * 2048, lds + (bufc) * 16384 + dst0);          \
        GLDS16(aSrc1 + (size_t)(kt) * 2048, lds + (bufc) * 16384 + dst1);          \
        GLDS16(bSrc0 + (size_t)(kt) * 2048, lds + (bufc) * 16384 + 8192 + dst0);   \
        GLDS16(bSrc1 + (size_t)(kt) * 2048, lds + (bufc) * 16384 + 8192 + dst1);   \
    } while (0)

    const int aRd = wm * 4096 + lane * 16;
    const int bRd = 8192 + wn * 4096 + lane * 16;

    i32x16 acc00 = (i32x16){0,0,0,0,0,0,0,0,0,0,0,0,0,0,0,0};
    i32x16 acc01 = acc00, acc10 = acc00, acc11 = acc00;

#define MMK(bufc) do {                                                             \
        const int ab = (bufc) * 16384 + aRd;                                       \
        const int bb = (bufc) * 16384 + bRd;                                       \
        i32x4 a00 = *(const i32x4*)&lds[ab];                                       \
        i32x4 a10 = *(const i32x4*)&lds[ab + 2048];                                \
        i32x4 b00 = *(const i32x4*)&lds[bb];                                       \
        i32x4 b10 = *(const i32x4*)&lds[bb + 2048];                                \
        i32x4 a01 = *(const i32x4*)&lds[ab + 1024];                                \
        i32x4 a11 = *(const i32x4*)&lds[ab + 3072];                                \
        i32x4 b01 = *(const i32x4*)&lds[bb + 1024];                                \
        i32x4 b11 = *(const i32x4*)&lds[bb + 3072];                                \
        __builtin_amdgcn_s_setprio(1);                                             \
        acc00 = __builtin_amdgcn_mfma_i32_32x32x32_i8(a00, b00, acc00, 0, 0, 0);   \
        acc01 = __builtin_amdgcn_mfma_i32_32x32x32_i8(a00, b10, acc01, 0, 0, 0);   \
        acc10 = __builtin_amdgcn_mfma_i32_32x32x32_i8(a10, b00, acc10, 0, 0, 0);   \
        acc11 = __builtin_amdgcn_mfma_i32_32x32x32_i8(a10, b10, acc11, 0, 0, 0);   \
        acc00 = __builtin_amdgcn_mfma_i32_32x32x32_i8(a01, b01, acc00, 0, 0, 0);   \
        acc01 = __builtin_amdgcn_mfma_i32_32x32x32_i8(a01, b11, acc01, 0, 0, 0);   \
        acc10 = __builtin_amdgcn_mfma_i32_32x32x32_i8(a11, b01, acc10, 0, 0, 0);   \
        acc11 = __builtin_amdgcn_mfma_i32_32x32x32_i8(a11, b11, acc11, 0, 0, 0);   \
        __builtin_amdgcn_s_setprio(0); } while (0)

    // step kt: stage kt+2 into buf (kt+2)%3 (read as kt-1 last step; WAR-safe
    // after BAR(kt-1)); compute kt from buf kt%3; gate forces kt+1; barrier.
#define STEP(cur, stg, kt) do {                                                    \
        STG(stg, (kt) + 2);                                                        \
        MMK(cur);                                                                  \
        VMW(4);                                                                    \
        BAR; } while (0)

    // ---- prologue: kt0 -> buf0, kt1 -> buf1; force kt0 (kt1's 4 stay in flight).
    STG(0, 0);
    STG(1, 1);
    VMW(4);
    BAR;

    #pragma unroll 1
    for (int j = 0; j < 10; j++) {
        const int kt = 3 * j;                  // kt = 0..29; stages kt2..kt31
        STEP(0, 2, kt);
        STEP(1, 0, kt + 1);
        STEP(2, 1, kt + 2);
    }
    // tail: kt30 (buf0), kt31 (buf1); no stages left.
    MMK(0);
    VMW(0);                                    // forces kt31 (last outstanding)
    BAR;
    MMK(1);

    // ---- epilogue: out = (max(acc * coef[row], 0))^2, direct nontemporal stores.
    // 32x32 C/D: col = lane&31, row = (r&3) + 8*(r>>2) + 4*(lane>>5)
    const int rb = brow * 128 + wm * 64 + 4 * kg;
    const int cb = bcol * 128 + wn * 64 + l31;
    #pragma unroll
    for (int mt = 0; mt < 2; mt++) {
        const i32x16 ac0 = mt ? acc10 : acc00;
        const i32x16 ac1 = mt ? acc11 : acc01;
        #pragma unroll
        for (int r = 0; r < 16; r++) {
            const int grow = rb + mt * 32 + (r & 3) + 8 * (r >> 2);
            const float c = coef[grow];
            float v0 = (float)ac0[r] * c; v0 = fmaxf(v0, 0.0f);
            float v1 = (float)ac1[r] * c; v1 = fmaxf(v1, 0.0f);
            __builtin_nontemporal_store(v0 * v0, &out[(size_t)grow * N_DIM + cb]);
            __builtin_nontemporal_store(v1 * v1, &out[(size_t)grow * N_DIM + cb + 32]);
        }
    }
#undef STG
#undef MMK
#undef STEP
}

// ---------------- launch ----------------
extern "C" void kernel_launch(void* const* d_in, const int* in_sizes, int n_in,
                              void* d_out, int out_size, void* d_ws, size_t ws_size,
                              hipStream_t stream) {
    const float* x = (const float*)d_in[0];   // [4,2048,2048] fp32
    const float* w = (const float*)d_in[1];   // [8192,2048] fp32
    float* out = (float*)d_out;               // [4,2048,8192] fp32

    char* ws = (char*)d_ws;
    float* sum   = (float*)ws;
    float* part  = (float*)(ws + 256);
    float* coef  = (float*)(ws + 49152);
    signed char* xqf = (signed char*)(ws + 131072);
    signed char* wqf = (signed char*)(ws + 131072 + 16777216);

    k_abs_partial<<<2048, 256, 0, stream>>>(w, part);
    k_abs_final<<<1, 256, 0, stream>>>(part, sum);
    k_wquant<<<4096, 256, 0, stream>>>(w, sum, wqf);
    k_xquant<<<M_DIM, 256, 0, stream>>>(x, sum, xqf, coef);
    k_gemm<<<dim3(4096), 256, 0, stream>>>(xqf, wqf, coef, out);
}

// Round 17
// 194.878 us; speedup vs baseline: 1.0227x; 1.0227x over previous
//
#include <hip/hip_runtime.h>
#include <hip/hip_bf16.h>

typedef __attribute__((ext_vector_type(4))) int i32x4;
typedef __attribute__((ext_vector_type(16))) int i32x16;

#define M_DIM 8192
#define N_DIM 8192
#define K_DIM 2048
#define WCOUNT (N_DIM * K_DIM)

// Fragment-major layout: frag[t32][kc][l] : byte = t32*65536 + kc*512 + l*16.
// One 32x32x32 MFMA operand fragment = contiguous 1024-B wave access.

// ---------------- kernel 1: per-block partial sums of |w| ----------------
__global__ __launch_bounds__(256) void k_abs_partial(const float* __restrict__ w,
                                                     float* __restrict__ part) {
    int tid = blockIdx.x * 256 + threadIdx.x;
    const float4* w4 = (const float4*)w;
    float s = 0.0f;
    const int total4 = WCOUNT / 4;
    for (int i = tid; i < total4; i += 2048 * 256) {
        float4 v = w4[i];
        s += fabsf(v.x) + fabsf(v.y) + fabsf(v.z) + fabsf(v.w);
    }
    #pragma unroll
    for (int off = 1; off < 64; off <<= 1) s += __shfl_xor(s, off);
    __shared__ float red[4];
    if ((threadIdx.x & 63) == 0) red[threadIdx.x >> 6] = s;
    __syncthreads();
    if (threadIdx.x == 0)
        part[blockIdx.x] = (red[0] + red[1]) + (red[2] + red[3]);
}

// ---------------- kernel 2: deterministic final reduce -> sum|w| ----------------
__global__ __launch_bounds__(256) void k_abs_final(const float* __restrict__ part,
                                                   float* __restrict__ sum) {
    int t = threadIdx.x;
    float s = 0.0f;
    #pragma unroll
    for (int i = 0; i < 8; i++) s += part[t + i * 256];
    #pragma unroll
    for (int off = 1; off < 64; off <<= 1) s += __shfl_xor(s, off);
    __shared__ float red[4];
    if ((t & 63) == 0) red[t >> 6] = s;
    __syncthreads();
    if (t == 0) sum[0] = (red[0] + red[1]) + (red[2] + red[3]);
}

// -------- kernel 3: ternary weight quant -> int8, fragment-major --------
__global__ __launch_bounds__(256) void k_wquant(const float* __restrict__ w,
                                                const float* __restrict__ sum,
                                                signed char* __restrict__ wqf) {
    const float thr = 0.5f * (sum[0] * (1.0f / 16777216.0f));
    const int g = blockIdx.x * 256 + threadIdx.x;
    const int n = g >> 7;
    const int kc = g & 127;
    const float4* wr = (const float4*)(w + (size_t)n * K_DIM + kc * 16);
    union { signed char c[16]; uint4 v; } pk;
    #pragma unroll
    for (int q = 0; q < 4; q++) {
        float4 v = wr[q];
        pk.c[q * 4 + 0] = v.x > thr ? 1 : (v.x < -thr ? -1 : 0);
        pk.c[q * 4 + 1] = v.y > thr ? 1 : (v.y < -thr ? -1 : 0);
        pk.c[q * 4 + 2] = v.z > thr ? 1 : (v.z < -thr ? -1 : 0);
        pk.c[q * 4 + 3] = v.w > thr ? 1 : (v.w < -thr ? -1 : 0);
    }
    *(uint4*)(wqf + (size_t)(n >> 5) * 65536 + kc * 512 + (n & 31) * 16) = pk.v;
}

// -------- kernel 4: activation quant -> int8 fragment-major + coef --------
__global__ __launch_bounds__(256) void k_xquant(const float* __restrict__ x,
                                                const float* __restrict__ sum,
                                                signed char* __restrict__ xqf,
                                                float* __restrict__ coef) {
    const int row = blockIdx.x;
    const int t = threadIdx.x;
    const float4* xr = (const float4*)(x + (size_t)row * K_DIM);
    float4 a = xr[t * 2];
    float4 b = xr[t * 2 + 1];
    float m = fmaxf(fmaxf(fmaxf(fabsf(a.x), fabsf(a.y)), fmaxf(fabsf(a.z), fabsf(a.w))),
                    fmaxf(fmaxf(fabsf(b.x), fabsf(b.y)), fmaxf(fabsf(b.z), fabsf(b.w))));
    #pragma unroll
    for (int off = 1; off < 64; off <<= 1) m = fmaxf(m, __shfl_xor(m, off));
    __shared__ float red[4];
    if ((t & 63) == 0) red[t >> 6] = m;
    __syncthreads();
    m = fmaxf(fmaxf(red[0], red[1]), fmaxf(red[2], red[3]));
    const float sc = fmaxf(m, 1e-5f);
    if (t == 0) coef[row] = (sum[0] * (1.0f / 16777216.0f)) / sc;
    const float r = 127.0f / sc;
    float q[8] = {a.x, a.y, a.z, a.w, b.x, b.y, b.z, b.w};
    union { signed char c[8]; uint2 v; } pk;
    #pragma unroll
    for (int j = 0; j < 8; j++) {
        float v = rintf(q[j] * r);
        v = fminf(fmaxf(v, -127.0f), 127.0f);
        pk.c[j] = (signed char)v;
    }
    *(uint2*)(xqf + (size_t)(row >> 5) * 65536 + (t >> 1) * 512
              + (row & 31) * 16 + (t & 1) * 8) = pk.v;
}

#define GLDS16(g, l)                                                                   \
    __builtin_amdgcn_global_load_lds((const __attribute__((address_space(1))) void*)(g), \
                                     (__attribute__((address_space(3))) void*)(l), 16, 0, 0)
#define BAR __builtin_amdgcn_s_barrier()
#define VMW(n) asm volatile("s_waitcnt vmcnt(" #n ")" ::: "memory")

// ---------------- kernel 5: 256x128 i8 GEMM, 4x2 wave tile, 2 blocks/CU -------
// Serial-port model (fits R11/R12 exactly: step = LDS-port-time + MFMA-time):
// minimize LDS bytes/MAC. Wave tile 128x64 (4x2 of 32x32) cuts reads/MAC 25%
// (ratio (Am+Bn)/(Am*Bn): 1.0 -> 0.75) and block 256x128 cuts DMA/MAC 25%.
// 256 thr / 4 waves (2Mx2N of 128x64); acc = 8 x i32x16 = 128 AGPR (+ ~75 arch
// VGPR, fits 2 waves/SIMD); LDS = 3-buf ring x 24 KB = 72 KB -> 2 blocks/CU
// (144 KB), keeping cross-block epilogue overlap. R12's proven STEP discipline:
// {MMK; BAR; STG(kt+3); VMW(12); BAR} — 6-load STGs, gate leaves kt+2,kt+3
// outstanding and forces kt+1 (2-step flight). Tail gates 12 -> 6 -> 0.
// All LDS accesses fragment-major contiguous (conflict-free, R11/R12-verified).
__global__ __launch_bounds__(256, 2) void k_gemm(const signed char* __restrict__ xqf,
                                                 const signed char* __restrict__ wqf,
                                                 const float* __restrict__ coef,
                                                 float* __restrict__ out) {
    __shared__ signed char lds[73728];   // 3 bufs x (A 16 KB + B 8 KB)

    const int t = threadIdx.x;
    const int lane = t & 63;
    const int wid = t >> 6;        // 0..3
    const int wm = wid >> 1;       // 0..1  (M half: 128 rows)
    const int wn = wid & 1;        // 0..1  (N half: 64 cols)
    const int l31 = lane & 31;
    const int kg = lane >> 5;

    // L2 map: XCD x owns brows [4x,4x+4) (A slice 4x512KB = 2MB); per XCD,
    // 16 groups of 4 bcols, each sweeping 4 brows x 4 bcols.
    const int bid = blockIdx.x;                // 0..2047
    const int xcd = bid & 7;
    const int idx = bid >> 3;                  // 0..255
    const int grp = idx >> 4;                  // 0..15
    const int w_ = idx & 15;
    const int bcol = grp * 4 + (w_ & 3);       // 0..63
    const int brow = xcd * 4 + (w_ >> 2);      // 0..31

    // staging: per K-tile, A = 8 t32-tiles (16 KB, 4 chunks/thread),
    // B = 4 t32-tiles (8 KB, 2 chunks/thread). Thread t stages chunk (t&127)
    // of tiles {2j + (t>>7)}; dest byte = j*4096 + t*16 (linear, wave-uniform
    // base + lane*16). Sources are contiguous 1024-B runs per wave.
    const int tsel = t >> 7;                   // 0..1
    const size_t aT0 = (size_t)(brow * 8 + 0 + tsel) * 65536 + (t & 127) * 16;
    const size_t aT1 = (size_t)(brow * 8 + 2 + tsel) * 65536 + (t & 127) * 16;
    const size_t aT2 = (size_t)(brow * 8 + 4 + tsel) * 65536 + (t & 127) * 16;
    const size_t aT3 = (size_t)(brow * 8 + 6 + tsel) * 65536 + (t & 127) * 16;
    const size_t bT0 = (size_t)(bcol * 4 + 0 + tsel) * 65536 + (t & 127) * 16;
    const size_t bT1 = (size_t)(bcol * 4 + 2 + tsel) * 65536 + (t & 127) * 16;
    const int dA = wid * 1024;                 // + j*4096; lane*16 implicit
    const int dB = 16384 + wid * 1024;

#define STG(bufc, kt) do {                                                         \
        const size_t ko_ = (size_t)(kt) * 2048;                                    \
        GLDS16(xqf + aT0 + ko_, lds + (bufc) * 24576 + dA);                        \
        GLDS16(xqf + aT1 + ko_, lds + (bufc) * 24576 + dA + 4096);                 \
        GLDS16(xqf + aT2 + ko_, lds + (bufc) * 24576 + dA + 8192);                 \
        GLDS16(xqf + aT3 + ko_, lds + (bufc) * 24576 + dA + 12288);                \
        GLDS16(wqf + bT0 + ko_, lds + (bufc) * 24576 + dB);                        \
        GLDS16(wqf + bT1 + ko_, lds + (bufc) * 24576 + dB + 4096);                 \
    } while (0)

    // fragment reads (contiguous per wave): A (mt,ks): wm*8192 + mt*2048 +
    // ks*1024 + lane*16; B (nt,ks): 16384 + wn*4096 + nt*2048 + ks*1024 + lane*16.
    const int aRd = wm * 8192 + lane * 16;
    const int bRd = 16384 + wn * 4096 + lane * 16;

    i32x16 c00 = (i32x16){0,0,0,0,0,0,0,0,0,0,0,0,0,0,0,0};
    i32x16 c01 = c00, c10 = c00, c11 = c00;
    i32x16 c20 = c00, c21 = c00, c30 = c00, c31 = c00;

#define MMK(bufc) do {                                                             \
        const int ab = (bufc) * 24576 + aRd;                                       \
        const int bb = (bufc) * 24576 + bRd;                                       \
        _Pragma("unroll")                                                          \
        for (int ks = 0; ks < 2; ks++) {                                           \
            i32x4 a0 = *(const i32x4*)&lds[ab + ks * 1024];                        \
            i32x4 a1 = *(const i32x4*)&lds[ab + 2048 + ks * 1024];                 \
            i32x4 a2 = *(const i32x4*)&lds[ab + 4096 + ks * 1024];                 \
            i32x4 a3 = *(const i32x4*)&lds[ab + 6144 + ks * 1024];                 \
            i32x4 b0 = *(const i32x4*)&lds[bb + ks * 1024];                        \
            i32x4 b1 = *(const i32x4*)&lds[bb + 2048 + ks * 1024];                 \
            __builtin_amdgcn_s_setprio(1);                                         \
            c00 = __builtin_amdgcn_mfma_i32_32x32x32_i8(a0, b0, c00, 0, 0, 0);     \
            c01 = __builtin_amdgcn_mfma_i32_32x32x32_i8(a0, b1, c01, 0, 0, 0);     \
            c10 = __builtin_amdgcn_mfma_i32_32x32x32_i8(a1, b0, c10, 0, 0, 0);     \
            c11 = __builtin_amdgcn_mfma_i32_32x32x32_i8(a1, b1, c11, 0, 0, 0);     \
            c20 = __builtin_amdgcn_mfma_i32_32x32x32_i8(a2, b0, c20, 0, 0, 0);     \
            c21 = __builtin_amdgcn_mfma_i32_32x32x32_i8(a2, b1, c21, 0, 0, 0);     \
            c30 = __builtin_amdgcn_mfma_i32_32x32x32_i8(a3, b0, c30, 0, 0, 0);     \
            c31 = __builtin_amdgcn_mfma_i32_32x32x32_i8(a3, b1, c31, 0, 0, 0);     \
            __builtin_amdgcn_s_setprio(0);                                         \
        } } while (0)

#define STEP(bufc, kt) do {                                                        \
        MMK(bufc);                                                                 \
        BAR;                                                                       \
        STG(bufc, (kt) + 3);                                                       \
        VMW(12);                                                                   \
        BAR; } while (0)

    // ---- prologue: kt0..kt2 -> bufs 0..2 (18 loads); force kt0.
    STG(0, 0); STG(1, 1); STG(2, 2);
    VMW(12);
    BAR;

    #pragma unroll 1
    for (int j = 0; j < 9; j++) {
        const int kt = 3 * j;                  // kt 0..26, stages 3..29
        STEP(0, kt);
        STEP(1, kt + 1);
        STEP(2, kt + 2);
    }
    STEP(0, 27);                               // stages 30; forces 28
    STEP(1, 28);                               // stages 31; forces 29
    MMK(2); BAR; VMW(6); BAR;                  // kt29; forces 30
    MMK(0); BAR; VMW(0); BAR;                  // kt30; forces 31
    MMK(1);                                    // kt31

    // ---- epilogue: out = (max(acc * coef[row], 0))^2, direct NT stores.
    // 32x32 C/D: col = lane&31, row = (r&3) + 8*(r>>2) + 4*(lane>>5)
    const int rb = brow * 256 + wm * 128 + 4 * kg;
    const int cb = bcol * 128 + wn * 64 + l31;
    #pragma unroll
    for (int mt = 0; mt < 4; mt++) {
        const i32x16 ac0 = (mt == 0) ? c00 : (mt == 1) ? c10 : (mt == 2) ? c20 : c30;
        const i32x16 ac1 = (mt == 0) ? c01 : (mt == 1) ? c11 : (mt == 2) ? c21 : c31;
        #pragma unroll
        for (int r = 0; r < 16; r++) {
            const int grow = rb + mt * 32 + (r & 3) + 8 * (r >> 2);
            const float c = coef[grow];
            float v0 = (float)ac0[r] * c; v0 = fmaxf(v0, 0.0f);
            float v1 = (float)ac1[r] * c; v1 = fmaxf(v1, 0.0f);
            __builtin_nontemporal_store(v0 * v0, &out[(size_t)grow * N_DIM + cb]);
            __builtin_nontemporal_store(v1 * v1, &out[(size_t)grow * N_DIM + cb + 32]);
        }
    }
#undef STG
#undef MMK
#undef STEP
}

// ---------------- launch ----------------
extern "C" void kernel_launch(void* const* d_in, const int* in_sizes, int n_in,
                              void* d_out, int out_size, void* d_ws, size_t ws_size,
                              hipStream_t stream) {
    const float* x = (const float*)d_in[0];   // [4,2048,2048] fp32
    const float* w = (const float*)d_in[1];   // [8192,2048] fp32
    float* out = (float*)d_out;               // [4,2048,8192] fp32

    char* ws = (char*)d_ws;
    float* sum   = (float*)ws;
    float* part  = (float*)(ws + 256);
    float* coef  = (float*)(ws + 49152);
    signed char* xqf = (signed char*)(ws + 131072);
    signed char* wqf = (signed char*)(ws + 131072 + 16777216);

    k_abs_partial<<<2048, 256, 0, stream>>>(w, part);
    k_abs_final<<<1, 256, 0, stream>>>(part, sum);
    k_wquant<<<4096, 256, 0, stream>>>(w, sum, wqf);
    k_xquant<<<M_DIM, 256, 0, stream>>>(x, sum, xqf, coef);
    k_gemm<<<dim3(2048), 256, 0, stream>>>(xqf, wqf, coef, out);
}